// Round 1
// baseline (218.478 us; speedup 1.0000x reference)
//
#include <hip/hip_runtime.h>
#include <hip/hip_bf16.h>

typedef __attribute__((ext_vector_type(8))) short short8;
typedef __attribute__((ext_vector_type(4))) float f32x4;

#define D 512
#define BM 64
#define BN 64
#define BK 64

__device__ inline unsigned pack2f(float lo, float hi) {
    __hip_bfloat162 v = __float22bfloat162_rn(make_float2(lo, hi));
    union { __hip_bfloat162 h; unsigned u; } cv;
    cv.h = v;
    return cv.u;
}

__device__ inline int4 pack8f(const float4& v0, const float4& v1, float sc) {
    int4 r;
    r.x = (int)pack2f(v0.x * sc, v0.y * sc);
    r.y = (int)pack2f(v0.z * sc, v0.w * sc);
    r.z = (int)pack2f(v1.x * sc, v1.y * sc);
    r.w = (int)pack2f(v1.z * sc, v1.w * sc);
    return r;
}

// Kernel 1: per-pair norms, fp32 diagonal cos, zero sumexp, optional bf16 cache.
__global__ __launch_bounds__(256) void norm_kernel(
    const float* __restrict__ x,
    float* __restrict__ pinv, float* __restrict__ ainv,
    float* __restrict__ diag, float* __restrict__ sumexp,
    __hip_bfloat16* __restrict__ Pn, __hip_bfloat16* __restrict__ An, int cached)
{
    const int i = blockIdx.x, t = threadIdx.x;
    const float2* ap = (const float2*)(x + (size_t)(2 * i) * D);
    const float2* pp = (const float2*)(x + (size_t)(2 * i + 1) * D);
    float2 a = ap[t], p = pp[t];
    float ssa = a.x * a.x + a.y * a.y;
    float ssp = p.x * p.x + p.y * p.y;
    float dt  = p.x * a.x + p.y * a.y;
#pragma unroll
    for (int m = 1; m < 64; m <<= 1) {
        ssa += __shfl_xor(ssa, m);
        ssp += __shfl_xor(ssp, m);
        dt  += __shfl_xor(dt, m);
    }
    __shared__ float red[3][4];
    if ((t & 63) == 0) { int wv = t >> 6; red[0][wv] = ssa; red[1][wv] = ssp; red[2][wv] = dt; }
    __syncthreads();
    ssa = red[0][0] + red[0][1] + red[0][2] + red[0][3];
    ssp = red[1][0] + red[1][1] + red[1][2] + red[1][3];
    dt  = red[2][0] + red[2][1] + red[2][2] + red[2][3];
    float an = sqrtf(ssa), pn = sqrtf(ssp);
    float ia = 1.0f / fmaxf(an, 1e-30f);
    float ip = 1.0f / fmaxf(pn, 1e-30f);
    if (t == 0) {
        ainv[i] = ia;
        pinv[i] = ip;
        diag[i] = dt / fmaxf(pn * an, 1e-8f);
        sumexp[i] = 0.0f;
    }
    if (cached) {
        ((__hip_bfloat162*)(Pn + (size_t)i * D))[t] = __float22bfloat162_rn(make_float2(p.x * ip, p.y * ip));
        ((__hip_bfloat162*)(An + (size_t)i * D))[t] = __float22bfloat162_rn(make_float2(a.x * ia, a.y * ia));
    }
}

// Kernel 2: fused GEMM (cos = P_hat * A_hat^T) + per-row sum of exp(w*cos - |w|).
// Grid: (8 column-splits, N/64 row blocks). Block: 256 threads = 4 waves (2x2 of 32x32).
template<bool CACHED>
__global__ __launch_bounds__(256, 2) void gemm_lse_kernel(
    const float* __restrict__ x,
    const __hip_bfloat16* __restrict__ Pn, const __hip_bfloat16* __restrict__ An,
    const float* __restrict__ pinv, const float* __restrict__ ainv,
    const float* __restrict__ wp, float* __restrict__ sumexp, int N)
{
    __shared__ __align__(16) unsigned char lds[81920];
    unsigned char* As = lds;                 // 64 x 512 bf16 (swizzled), 65536 B
    unsigned char* Bs = lds + 65536;         // 2 x (64 x 64 bf16), 2 x 8192 B

    const int t = threadIdx.x;
    const int rb = blockIdx.y, cs = blockIdx.x;
    const int lane = t & 63, w = t >> 6;
    const int wr = w >> 1, wc = w & 1;
    const int l15 = lane & 15, lhi = lane >> 4;

    const int colsPer = N >> 3;              // 1024
    const int CT = colsPer / BN;             // 16
    const int Q = CT * (D / BK);             // 128

    // ---- stage A tile once: rows rb*64 .. +64, full K=512 ----
    {
        int r = t >> 2;                      // 0..63
        int kq = (t & 3) << 7;               // 0,128,256,384
        int grow = rb * BM + r;
        if (CACHED) {
            const int4* src = (const int4*)(Pn + (size_t)grow * D);
#pragma unroll
            for (int i2 = 0; i2 < 16; ++i2) {
                int k0 = kq + i2 * 8;
                int4 v = src[k0 >> 3];
                *(int4*)(As + r * 1024 + ((k0 * 2) ^ ((r & 7) << 4))) = v;
            }
        } else {
            const float4* src = (const float4*)(x + (size_t)(2 * grow + 1) * D);
            float sc = pinv[grow];
#pragma unroll
            for (int i2 = 0; i2 < 16; ++i2) {
                int k0 = kq + i2 * 8;
                float4 v0 = src[k0 >> 2], v1 = src[(k0 >> 2) + 1];
                *(int4*)(As + r * 1024 + ((k0 * 2) ^ ((r & 7) << 4))) = pack8f(v0, v1, sc);
            }
        }
    }

    const int cl = t >> 2;                   // 0..63 local col
    const int kq = (t & 3) << 4;             // 0,16,32,48 within 64-k chunk

    auto loadB = [&](int q, int4& oa, int4& ob) {
        int ct = q >> 3, kc = q & 7;
        int c = cs * colsPer + ct * BN + cl;
        int k = kc * BK + kq;
        if (CACHED) {
            const int4* src = (const int4*)(An + (size_t)c * D + k);
            oa = src[0]; ob = src[1];
        } else {
            const float4* src = (const float4*)(x + (size_t)(2 * c) * D + k);
            float sc = ainv[c];
            float4 v0 = src[0], v1 = src[1], v2 = src[2], v3 = src[3];
            oa = pack8f(v0, v1, sc);
            ob = pack8f(v2, v3, sc);
        }
    };
    auto writeB = [&](int buf, const int4& oa, const int4& ob) {
        unsigned char* bb = Bs + buf * 8192 + cl * 128;
        int kb0 = kq * 2;
        *(int4*)(bb + (kb0 ^ ((cl & 7) << 4))) = oa;
        *(int4*)(bb + ((kb0 + 16) ^ ((cl & 7) << 4))) = ob;
    };

    const float wv = *wp;
    const float s = fabsf(wv);

    int4 ba, bb2;
    loadB(0, ba, bb2);
    __syncthreads();           // A tile visible
    writeB(0, ba, bb2);
    __syncthreads();           // B chunk 0 visible

    f32x4 acc[2][2];
    float rs[2][4];
#pragma unroll
    for (int mi = 0; mi < 2; ++mi) {
#pragma unroll
        for (int j = 0; j < 4; ++j) rs[mi][j] = 0.0f;
#pragma unroll
        for (int ni = 0; ni < 2; ++ni) {
#pragma unroll
            for (int j = 0; j < 4; ++j) acc[mi][ni][j] = 0.0f;
        }
    }

    for (int q = 0; q < Q; ++q) {
        const int kc = q & 7;
        const bool more = (q + 1 < Q);
        if (more) loadB(q + 1, ba, bb2);     // issue global loads early (hide under MFMA)
        const unsigned char* Bp = Bs + (q & 1) * 8192;
#pragma unroll
        for (int ks = 0; ks < 2; ++ks) {
            int ka = kc * 64 + ks * 32 + lhi * 8;
            int ra0 = wr * 32 + l15, ra1 = ra0 + 16;
            short8 a0 = *(const short8*)(As + ra0 * 1024 + ((ka * 2) ^ ((ra0 & 7) << 4)));
            short8 a1 = *(const short8*)(As + ra1 * 1024 + ((ka * 2) ^ ((ra1 & 7) << 4)));
            int kb = ks * 32 + lhi * 8;
            int c0 = wc * 32 + l15, c1 = c0 + 16;
            short8 b0 = *(const short8*)(Bp + c0 * 128 + ((kb * 2) ^ ((c0 & 7) << 4)));
            short8 b1 = *(const short8*)(Bp + c1 * 128 + ((kb * 2) ^ ((c1 & 7) << 4)));
            acc[0][0] = __builtin_amdgcn_mfma_f32_16x16x32_bf16(a0, b0, acc[0][0], 0, 0, 0);
            acc[0][1] = __builtin_amdgcn_mfma_f32_16x16x32_bf16(a0, b1, acc[0][1], 0, 0, 0);
            acc[1][0] = __builtin_amdgcn_mfma_f32_16x16x32_bf16(a1, b0, acc[1][0], 0, 0, 0);
            acc[1][1] = __builtin_amdgcn_mfma_f32_16x16x32_bf16(a1, b1, acc[1][1], 0, 0, 0);
        }
        if (kc == 7) {
            // finished a full-K 64x64 tile: exp and accumulate row partials
#pragma unroll
            for (int mi = 0; mi < 2; ++mi) {
#pragma unroll
                for (int ni = 0; ni < 2; ++ni) {
#pragma unroll
                    for (int j = 0; j < 4; ++j) {
                        rs[mi][j] += __expf(acc[mi][ni][j] * wv - s);
                        acc[mi][ni][j] = 0.0f;
                    }
                }
            }
        }
        if (more) {
            __syncthreads();
            writeB((q + 1) & 1, ba, bb2);
            __syncthreads();
        }
    }

    // reduce row partials across the 16 lanes of each row group, one atomic per row
#pragma unroll
    for (int mi = 0; mi < 2; ++mi) {
#pragma unroll
        for (int j = 0; j < 4; ++j) {
            float v = rs[mi][j];
            v += __shfl_xor(v, 1);
            v += __shfl_xor(v, 2);
            v += __shfl_xor(v, 4);
            v += __shfl_xor(v, 8);
            if (l15 == 0) {
                int row = rb * BM + wr * 32 + mi * 16 + lhi * 4 + j;
                atomicAdd(&sumexp[row], v);
            }
        }
    }
}

// Kernel 3: loss_i = |w| + log(sumexp_i) - w*diag_i ; out = mean(loss)
__global__ __launch_bounds__(256) void finalize_kernel(
    const float* __restrict__ sumexp, const float* __restrict__ diag,
    const float* __restrict__ wp, float* __restrict__ out, int N)
{
    const int t = threadIdx.x;
    const float w = *wp;
    const float s = fabsf(w);
    float acc = 0.0f;
    for (int i = t; i < N; i += 256)
        acc += s + logf(sumexp[i]) - w * diag[i];
#pragma unroll
    for (int m = 1; m < 64; m <<= 1) acc += __shfl_xor(acc, m);
    __shared__ float red[4];
    if ((t & 63) == 0) red[t >> 6] = acc;
    __syncthreads();
    if (t == 0) out[0] = (red[0] + red[1] + red[2] + red[3]) / (float)N;
}

extern "C" void kernel_launch(void* const* d_in, const int* in_sizes, int n_in,
                              void* d_out, int out_size, void* d_ws, size_t ws_size,
                              hipStream_t stream) {
    const float* x  = (const float*)d_in[0];
    const float* wp = (const float*)d_in[1];
    // b (d_in[2]) cancels in log_softmax diagonal term.

    const int N = in_sizes[0] / (2 * D);     // 8192

    char* ws = (char*)d_ws;
    size_t nf = (size_t)N * 4;
    float* pinv   = (float*)(ws);
    float* ainv   = (float*)(ws + nf);
    float* diag   = (float*)(ws + 2 * nf);
    float* sumexp = (float*)(ws + 3 * nf);
    size_t base = (4 * nf + 255) & ~(size_t)255;
    __hip_bfloat16* Pn = (__hip_bfloat16*)(ws + base);
    __hip_bfloat16* An = (__hip_bfloat16*)(ws + base + (size_t)N * D * 2);
    const bool cached = ws_size >= base + (size_t)N * D * 4;

    norm_kernel<<<N, 256, 0, stream>>>(x, pinv, ainv, diag, sumexp, Pn, An, cached ? 1 : 0);

    dim3 grid(8, N / BM);
    if (cached)
        gemm_lse_kernel<true><<<grid, 256, 0, stream>>>(x, Pn, An, pinv, ainv, wp, sumexp, N);
    else
        gemm_lse_kernel<false><<<grid, 256, 0, stream>>>(x, Pn, An, pinv, ainv, wp, sumexp, N);

    finalize_kernel<<<1, 256, 0, stream>>>(sumexp, diag, wp, (float*)d_out, N);
}